// Round 12
// baseline (1103.911 us; speedup 1.0000x reference)
//
#include <hip/hip_runtime.h>

#define NN 512
#define MM 512
#define NEO 510
#define PLANE (NN * MM)          // 262144
#define STATE_CH 26
#define OUT_DIM 28
#define FEAT 245
#define NW (FEAT * OUT_DIM)      // 6860
#define THRESH 0.0007f

// Fused prologue. blockIdx.x < 256: transpose state0 -> planar A and B.
// blockIdx.x >= 256: W12 = W1@W2, b12 = b1@W2+b2.
__global__ __launch_bounds__(256) void prep_all(
    const float* __restrict__ s0, float* __restrict__ A, float* __restrict__ B,
    const float* __restrict__ W1, const float* __restrict__ b1,
    const float* __restrict__ W2, const float* __restrict__ b2,
    float* __restrict__ W12, float* __restrict__ b12) {
  if (blockIdx.x < 256) {
    const int base = (blockIdx.x * 256 + threadIdx.x) * 4;  // 4 consecutive cells
    float v[4][STATE_CH];
    const float* src = s0 + (size_t)base * STATE_CH;
#pragma unroll
    for (int q = 0; q < 4; ++q)
#pragma unroll
      for (int c = 0; c < STATE_CH; ++c) v[q][c] = src[q * STATE_CH + c];
#pragma unroll
    for (int c = 0; c < STATE_CH; ++c) {
      float4 w = make_float4(v[0][c], v[1][c], v[2][c], v[3][c]);
      *(float4*)(A + (size_t)c * PLANE + base) = w;
      *(float4*)(B + (size_t)c * PLANE + base) = w;
    }
  } else {
    const int t = (blockIdx.x - 256) * 256 + threadIdx.x;
    if (t < NW) {
      const int f = t / OUT_DIM, k = t - f * OUT_DIM;
      float s = 0.0f;
      for (int jj = 0; jj < FEAT; ++jj) s = fmaf(W1[f * FEAT + jj], W2[jj * OUT_DIM + k], s);
      W12[t] = s;
    } else if (t < NW + OUT_DIM) {
      const int k = t - NW;
      float s = b2[k];
      for (int jj = 0; jj < FEAT; ++jj) s = fmaf(b1[jj], W2[jj * OUT_DIM + k], s);
      b12[k] = s;
    }
  }
}

// Epilogue pos-term FMAs (posx row then posy row), order identical to reference.
#define POSEPI(ACC, Q)                                                        \
  {                                                                           \
    const float px = (float)(pq[Q].x - 256) * (1.0f / 256.0f);                \
    const float py = (float)(pq[Q].y - 256) * (1.0f / 256.0f);                \
    _Pragma("unroll") for (int k = 0; k < OUT_DIM; ++k)                       \
        ACC[k] = fmaf(px, wp[k], ACC[k]);                                     \
    _Pragma("unroll") for (int k = 0; k < OUT_DIM; ++k)                       \
        ACC[k] = fmaf(py, wp[OUT_DIM + k], ACC[k]);                           \
  }

#define STORE_STEP(ACC, Q)                                                    \
  if (act[Q]) {                                                               \
    const int nb = nbs[Q];                                                    \
    const float ax = ACC[26], ay = ACC[27];                                   \
    int dx = (ax < -THRESH) ? -1 : ((ax > THRESH) ? 1 : 0);                   \
    int dy = (ay < -THRESH) ? -1 : ((ay > THRESH) ? 1 : 0);                   \
    int nx = min(max(pq[Q].x + dx, 0), NEO - 1);                              \
    int ny = min(max(pq[Q].y + dy, 0), NEO - 1);                              \
    ((int2*)pnew)[cells[Q]] = make_int2(nx, ny);                              \
    _Pragma("unroll") for (int c = 0; c < STATE_CH; ++c)                      \
        snew[c * PLANE + nb] = sold[c * PLANE + nb] + ACC[c];                 \
  }

#define STORE_LAST(ACC, Q)                                                    \
  if (act[Q]) {                                                               \
    const int nb = nbs[Q];                                                    \
    float2* o0 = (float2*)(out0 + (size_t)cells[Q] * 10);                     \
    _Pragma("unroll") for (int c = 0; c < 5; ++c) {                           \
      float2 v;                                                               \
      v.x = sold[(16 + 2 * c) * PLANE + nb] + ACC[16 + 2 * c];                \
      v.y = sold[(17 + 2 * c) * PLANE + nb] + ACC[17 + 2 * c];                \
      o0[c] = v;                                                              \
    }                                                                         \
    float4* o1 = (float4*)(out1 + (size_t)cells[Q] * OUT_DIM);                \
    _Pragma("unroll") for (int r = 0; r < 7; ++r)                             \
        o1[r] = make_float4(ACC[4 * r], ACC[4 * r + 1], ACC[4 * r + 2],       \
                            ACC[4 * r + 3]);                                  \
  }

template <bool LAST>
__global__ __launch_bounds__(256, 2) void nca_step(
    const float* __restrict__ img, const float* __restrict__ sold, float* __restrict__ snew,
    const int* __restrict__ pold, int* __restrict__ pnew,
    const float* __restrict__ W12, const float* __restrict__ b12,
    float* __restrict__ out0, float* __restrict__ out1) {
  // 256 blocks; XCD swizzle: XCD k gets bands 4k..4k+3 (64 contiguous rows,
  // 64*512*26*4B = 3.4 MB state <= 4 MB per-XCD L2).
  const int bid = (int)blockIdx.x;
  const int lin = (bid & 7) * 32 + (bid >> 3);
  const int band = lin >> 3;               // 0..31, 16 rows each
  const int jb   = lin & 7;                // 0..7, 64 cols each
  const int lane = (int)(threadIdx.x & 63);
  const int wv   = (int)(threadIdx.x >> 6);
  const int j = jb * 64 + lane;
  if (j >= NEO) return;

  // C=4 cells per thread: rows band*16 + wv + {0,4,8,12}, same column j.
  int2 pq[4]; const float* rp[4]; const float* ip[4];
  bool act[4]; int cells[4]; int nbs[4];
#pragma unroll
  for (int q = 0; q < 4; ++q) {
    const int iq = band * 16 + wv + 4 * q;
    act[q] = (iq < NEO);
    const int ic = act[q] ? iq : (NEO - 1);   // clamp: compute garbage, store guarded
    cells[q] = ic * NEO + j;
    nbs[q] = (ic + 1) * MM + (j + 1);
    pq[q] = ((const int2*)pold)[cells[q]];
    rp[q] = sold + ic * MM + j;
    ip[q] = img + pq[q].x * MM + pq[q].y;
  }

  float acc0[OUT_DIM], acc1[OUT_DIM], acc2[OUT_DIM], acc3[OUT_DIM];
#pragma unroll
  for (int k = 0; k < OUT_DIM; ++k) {
    const float b = b12[k];
    acc0[k] = b; acc1[k] = b; acc2[k] = b; acc3[k] = b;
  }

  const float* wp = W12;
  int djc = 0;
  // rolling 3-slot x 4-cell val window; all indices compile-time (full unroll)
  float sl[3][4];

#pragma unroll 1
  for (int ps = 0; ps < 9; ++ps) {
    // prefetch t=0 (img at perception window) and t=1 (state channel 0)
#pragma unroll
    for (int q = 0; q < 4; ++q) sl[0][q] = *ip[q];
#pragma unroll
    for (int q = 0; q < 4; ++q) sl[1][q] = rp[q][0];
#pragma unroll
    for (int t = 0; t < 27; ++t) {
      if (t < 25) {                        // prefetch t+2 (state channel t+1)
#pragma unroll
        for (int q = 0; q < 4; ++q) sl[(t + 2) % 3][q] = rp[q][(t + 1) * PLANE];
      }
      const float* wt = wp + t * OUT_DIM;  // wave-uniform -> scalar loads
#pragma unroll
      for (int k = 0; k < OUT_DIM; ++k) {
        const float w = wt[k];             // one s_load feeds 4 FMAs
        acc0[k] = fmaf(sl[t % 3][0], w, acc0[k]);
        acc1[k] = fmaf(sl[t % 3][1], w, acc1[k]);
        acc2[k] = fmaf(sl[t % 3][2], w, acc2[k]);
        acc3[k] = fmaf(sl[t % 3][3], w, acc3[k]);
      }
    }
    wp += 27 * OUT_DIM;
    if (ps != 8) {                         // walk (di,dj); guard keeps ptrs in-bounds
      const int d = (djc == 2) ? (MM - 2) : 1;
      djc = (djc == 2) ? 0 : djc + 1;
#pragma unroll
      for (int q = 0; q < 4; ++q) { rp[q] += d; ip[q] += d; }
    }
  }

  POSEPI(acc0, 0) POSEPI(acc1, 1) POSEPI(acc2, 2) POSEPI(acc3, 3)

  if (!LAST) {
    STORE_STEP(acc0, 0) STORE_STEP(acc1, 1) STORE_STEP(acc2, 2) STORE_STEP(acc3, 3)
  } else {
    STORE_LAST(acc0, 0) STORE_LAST(acc1, 1) STORE_LAST(acc2, 2) STORE_LAST(acc3, 3)
  }
}

extern "C" void kernel_launch(void* const* d_in, const int* in_sizes, int n_in,
                              void* d_out, int out_size, void* d_ws, size_t ws_size,
                              hipStream_t stream) {
  const float* img    = (const float*)d_in[0];
  const float* state0 = (const float*)d_in[1];
  const int*   perc0  = (const int*)d_in[2];
  const float* W1     = (const float*)d_in[3];
  const float* b1     = (const float*)d_in[4];
  const float* W2     = (const float*)d_in[5];
  const float* b2     = (const float*)d_in[6];
  float* out = (float*)d_out;

  float* stateA = (float*)d_ws;                              // 26*PLANE f32
  float* stateB = stateA + (size_t)STATE_CH * PLANE;         // 26*PLANE f32
  int*   percA  = (int*)(stateB + (size_t)STATE_CH * PLANE); // 510*510*2 i32
  int*   percB  = percA + (size_t)NEO * NEO * 2;
  float* W12    = (float*)(percB + (size_t)NEO * NEO * 2);   // 6860 f32
  float* b12    = W12 + NW;

  float* out0 = out;                           // 510*510*10
  float* out1 = out + (size_t)NEO * NEO * 10;  // 510*510*28

  prep_all<<<dim3(256 + 27), dim3(256), 0, stream>>>(state0, stateA, stateB,
                                                     W1, b1, W2, b2, W12, b12);

  dim3 grid(256), block(256);
  nca_step<false><<<grid, block, 0, stream>>>(img, stateA, stateB, perc0, percB, W12, b12, nullptr, nullptr);
  nca_step<false><<<grid, block, 0, stream>>>(img, stateB, stateA, percB, percA, W12, b12, nullptr, nullptr);
  nca_step<false><<<grid, block, 0, stream>>>(img, stateA, stateB, percA, percB, W12, b12, nullptr, nullptr);
  nca_step<true ><<<grid, block, 0, stream>>>(img, stateB, nullptr, percB, nullptr, W12, b12, out0, out1);
}